// Round 13
// baseline (182.816 us; speedup 1.0000x reference)
//
#include <hip/hip_runtime.h>

#define NB 16
#define TT 6000
#define HH 256
#define CC 105
#define MIN_GAP_ 19
#define REF_GAP_ 9

using short8  = __attribute__((ext_vector_type(8))) short;
using short4v = __attribute__((ext_vector_type(4))) short;
using f32x4   = __attribute__((ext_vector_type(4))) float;

static __device__ __forceinline__ short f2bf(float x) {
  unsigned u = __builtin_bit_cast(unsigned, x);
  unsigned r = (u + 0x7FFFu + ((u >> 16) & 1u)) >> 16;   // RNE
  return (short)r;
}

// ---- one-time W (channels 1..104) f32 -> bf16, zero-padded to 112 rows ----
__global__ __launch_bounds__(256) void wconv_kernel(
    const float* __restrict__ W, unsigned short* __restrict__ Wb) {
  const int idx = blockIdx.x * 256 + threadIdx.x;   // 0..28671 (112*256)
  const int c = idx >> 8, k = idx & 255;
  const float v = (c < CC - 1) ? W[(size_t)(c + 1) * HH + k] : 0.f;
  Wb[idx] = (unsigned short)f2bf(v);
}

// ---- GEMM: R8 config (best total), at 2x grid for direct top-5 visibility.
// B in LDS (56KB swizzled, 2 blocks/CU), A per-lane global, 16-deep MLP.
#define NGRID 750

__global__ __launch_bounds__(512, 4) void gemm_mfma(
    const float* __restrict__ feat, const float* __restrict__ W,
    const float* __restrict__ bias, const unsigned short* __restrict__ Wb,
    float* __restrict__ out0, float* __restrict__ out1) {
  __shared__ __align__(16) unsigned short bS[112 * 256];   // 56 KB, swizzled
  const int tid  = threadIdx.x;
  const int wv   = tid >> 6;        // wave 0..7
  const int lane = tid & 63;
  const int rl   = lane & 15;
  const int kg   = lane >> 4;
  const int bid  = (blockIdx.x >= NGRID) ? blockIdx.x - NGRID : blockIdx.x;
  const int row  = bid * 128 + wv * 16 + rl;
  const float* frow = feat + (size_t)row * HH;

  // ---- issue B stage loads (7 x 16B per thread, coalesced, L2-hit) ----
  short8 breg[7];
#pragma unroll
  for (int i = 0; i < 7; i++)
    breg[i] = *reinterpret_cast<const short8*>(Wb + (((size_t)(i * 512 + tid)) << 3));

  // ---- issue ALL 16 A loads (256B/lane in flight) ----
  float4 areg[16];
#pragma unroll
  for (int ks = 0; ks < 8; ks++) {
    const int kk = ks * 32 + kg * 8;
    areg[2 * ks]     = *reinterpret_cast<const float4*>(frow + kk);
    areg[2 * ks + 1] = *reinterpret_cast<const float4*>(frow + kk + 4);
  }

  // ---- B: swizzled LDS writes ----
#pragma unroll
  for (int i = 0; i < 7; i++) {
    const int byte = (i * 512 + tid) << 4;
    const int brow = byte >> 9;
    const int boff = byte & 511;
    *reinterpret_cast<short8*>(
        (char*)bS + (brow << 9) + (boff ^ ((brow & 7) << 4))) = breg[i];
  }
  __syncthreads();

  // ---- main loop: c0 f32 dot (bit-identical order) + bf16 MFMA sweep ----
  const int xr = (rl & 7) << 4;
  f32x4 acc[7];
#pragma unroll
  for (int n = 0; n < 7; n++) acc[n] = (f32x4){0.f, 0.f, 0.f, 0.f};
  float c0 = 0.f;

#pragma unroll
  for (int ks = 0; ks < 8; ks++) {
    const int kk = ks * 32 + kg * 8;
    const float4 a0 = areg[2 * ks];
    const float4 a1 = areg[2 * ks + 1];
    const float4 w0a = *reinterpret_cast<const float4*>(W + kk);
    const float4 w0b = *reinterpret_cast<const float4*>(W + kk + 4);
    c0 = fmaf(a0.x, w0a.x, c0); c0 = fmaf(a0.y, w0a.y, c0);
    c0 = fmaf(a0.z, w0a.z, c0); c0 = fmaf(a0.w, w0a.w, c0);
    c0 = fmaf(a1.x, w0b.x, c0); c0 = fmaf(a1.y, w0b.y, c0);
    c0 = fmaf(a1.z, w0b.z, c0); c0 = fmaf(a1.w, w0b.w, c0);

    short8 av;
    av[0] = f2bf(a0.x); av[1] = f2bf(a0.y); av[2] = f2bf(a0.z); av[3] = f2bf(a0.w);
    av[4] = f2bf(a1.x); av[5] = f2bf(a1.y); av[6] = f2bf(a1.z); av[7] = f2bf(a1.w);

    const int boff = (ks * 64 + kg * 16) ^ xr;
    const char* bbase = (const char*)bS + boff;
    short8 bv[7];
#pragma unroll
    for (int n = 0; n < 7; n++)
      bv[n] = *reinterpret_cast<const short8*>(bbase + ((n * 16 + rl) << 9));
#pragma unroll
    for (int n = 0; n < 7; n++)
      acc[n] = __builtin_amdgcn_mfma_f32_16x16x32_bf16(av, bv[n], acc[n], 0, 0, 0);
  }

  c0 += __shfl_xor(c0, 16);
  c0 += __shfl_xor(c0, 32);
  if (kg == 0) out0[row] = fminf(fmaxf(c0 + bias[0], -16.f), 16.f);

  const int rbase = bid * 128 + wv * 16 + kg * 4;
#pragma unroll
  for (int n = 0; n < 7; n++) {
    const int c = n * 16 + rl;
    if (c < CC - 1) {
      const float bb = bias[c + 1];
#pragma unroll
      for (int r = 0; r < 4; r++)
        out1[(size_t)(rbase + r) * (CC - 1) + c] = acc[n][r] + bb;
    }
  }
}

// ---- phase: REPS=4 internal repetition for direct top-5 visibility.
// Each rep is a pure function of the inputs (all state re-initialized),
// so output is identical to a single pass. dur/4 = true phase cost.
#define NW 192
#define NW_LAST 187
#define CHUNK 32
#define NCLS 19
#define MAXRUNS 3072
#define MAXCH 96
#define REPS 4

__global__ __launch_bounds__(512) void phase_kernel(
    const float* __restrict__ bd_logits,
    const int* __restrict__ word_bd,
    const float* __restrict__ non_padding,
    float* __restrict__ out2) {
  __shared__ __align__(16) float lbuf[TT];
  __shared__ unsigned char wbuf[TT];
  __shared__ int res[TT];
  __shared__ unsigned bdbits[NW];
  __shared__ int runIdx[MAXRUNS];
  __shared__ int outLast[MAXCH][NCLS + 1];
  __shared__ int chP0[MAXCH];
  __shared__ int inL[MAXCH + 1];
  __shared__ int wsum[8];
  __shared__ int wbase[8];
  __shared__ int L_sh, nruns_sh;

  const int b = blockIdx.x;
  const int tid = threadIdx.x;
  const int lane = tid & 63;
  const int wid = tid >> 6;

  for (int rep = 0; rep < REPS; rep++) {
    if (tid == 0) L_sh = 0;
    __syncthreads();

    int cnt_np = 0;
#pragma unroll
    for (int k = 0; k < 12; k++) {
      const int j = k * 512 + tid;
      bool pred = false;
      if (j < TT) {
        const float l = bd_logits[(size_t)b * TT + j];
        lbuf[j] = l;
        pred = l > 0.f;
        wbuf[j] = (unsigned char)word_bd[(size_t)b * TT + j];
        res[j] = 0;
        cnt_np += (non_padding[(size_t)b * TT + j] != 0.f) ? 1 : 0;
      }
      const unsigned long long m = __ballot(pred);
      if (lane == 0) {
        const int w0 = (k * 512 + (tid & ~63)) >> 5;
        bdbits[w0]     = (unsigned)m;
        bdbits[w0 + 1] = (unsigned)(m >> 32);
      }
    }
#pragma unroll
    for (int off = 32; off; off >>= 1) cnt_np += __shfl_xor(cnt_np, off);
    if (lane == 0) atomicAdd(&L_sh, cnt_np);
    __syncthreads();

    int cnt = 0;
    unsigned ends = 0;
    if (tid < NW) {
      const unsigned cur = bdbits[tid];
      const unsigned pb = tid ? (bdbits[tid - 1] >> 31) : 0u;
      ends = ((cur << 1) | pb) & ~cur;
      if (tid == NW_LAST) ends &= 0xFFFFu;
      cnt = __popc(ends);
    }
    int v = cnt;
#pragma unroll
    for (int off = 1; off < 64; off <<= 1) {
      const int t = __shfl_up(v, off);
      if (lane >= off) v += t;
    }
    if (lane == 63) wsum[wid] = v;
    __syncthreads();
    if (tid == 0) {
      int s = 0;
#pragma unroll
      for (int w = 0; w < 8; w++) { wbase[w] = s; s += wsum[w]; }
      nruns_sh = s;
    }
    __syncthreads();
    int slot = wbase[wid] + v - cnt;

    if (ends) {
      unsigned m = ends;
      while (m) {
        const int bit = __builtin_ctz(m);
        m &= m - 1;
        const int e = tid * 32 + bit;
        const int eb = e - 1;
        int w = eb >> 5;
        const int bb = eb & 31;
        const unsigned z = bdbits[w] << (31 - bb);
        const unsigned nz = ~z;
        int run = nz ? __builtin_clz(nz) : 32;
        if (run == bb + 1) {
          while (w > 0) {
            w--;
            const unsigned nx = ~bdbits[w];
            const int t2 = nx ? __builtin_clz(nx) : 32;
            run += t2;
            if (t2 < 32) break;
          }
        }
        const int s = e - run;
        float mv = lbuf[s];
        int mi = s;
        for (int i = s + 1; i < e; i++) {
          const float val = lbuf[i];
          if (val > mv) { mv = val; mi = i; }
        }
        runIdx[slot++] = mi;
      }
    }
    __syncthreads();

    const int n = nruns_sh;
    const int nch = (n + CHUNK - 1) / CHUNK;
    for (int f = tid; f < nch * NCLS; f += 512) {
      const int ch = f / NCLS;
      const int cls = f - ch * NCLS;
      const int s = ch * CHUNK;
      const int e = (s + CHUNK < n) ? s + CHUNK : n;
      const int p0 = runIdx[s];
      if (cls == NCLS - 1) chP0[ch] = p0;
      int last = (cls < 18) ? (p0 - 18 + cls) : -1;
      for (int i = s; i < e; i++) {
        int bd = runIdx[i];
        if (last > 0 && bd - last < MIN_GAP_) {
          const int sum = bd + last;
          const int h = sum >> 1;
          bd = (sum & 1) ? (h + (h & 1)) : h;
        }
        last = bd;
      }
      outLast[ch][cls] = last;
    }
    __syncthreads();

    if (wid == 0) {
      int q = -1;
      int row = (lane < NCLS && nch > 0) ? outLast[0][lane] : -1;
      for (int ch = 0; ch < nch; ch++) {
        const int rown = (lane < NCLS && ch + 1 < nch) ? outLast[ch + 1][lane] : -1;
        const int p0 = chP0[ch];
        const int cls = (q > 0 && p0 - q < MIN_GAP_) ? (q - (p0 - 18)) : (NCLS - 1);
        if (lane == 0) inL[ch] = q;
        q = __shfl(row, cls);
        row = rown;
      }
      if (lane == 0) inL[nch] = q;
    }
    __syncthreads();

    for (int ch = tid; ch < nch; ch += 512) {
      const int s = ch * CHUNK;
      const int e = (s + CHUNK < n) ? s + CHUNK : n;
      const int qin = inL[ch];
      const int qout = inL[ch + 1];
      if (qin >= 0 && qin != qout) res[qin] = 1;
      int last = qin;
      for (int i = s; i < e; i++) {
        int bd = runIdx[i];
        if (last > 0 && bd - last < MIN_GAP_) {
          const int sum = bd + last;
          const int h = sum >> 1;
          bd = (sum & 1) ? (h + (h & 1)) : h;
          if (last != qout) res[last] = 0;
        }
        if (bd != qout) res[bd] = 1;
        last = bd;
      }
    }
    if (tid == 0 && n > 0) res[inL[nch]] = 1;
    __syncthreads();

    for (int j = tid; j < TT; j += 512) {
      if (wbuf[j] != 1) continue;
      const int lo = (j - REF_GAP_ < 0) ? 0 : j - REF_GAP_;
      const int hi = (j + REF_GAP_ - 1 > TT - 1) ? TT - 1 : j + REF_GAP_ - 1;
      int seg = 0;
      for (int w = lo; w <= hi; w++) seg += res[w];
      if (seg == 0) {
        res[j] = 1;
      } else if (seg == 1) {
        if (res[j] != 1) {
          for (int w = lo; w <= hi; w++) res[w] = (int)wbuf[w];
        }
      } else {
        int zidx = -1;
        for (int k = 1; k <= REF_GAP_; k++) {
          const int li = (j - k < 0) ? 0 : j - k;
          const int ri = (j + k > TT - 1) ? TT - 1 : j + k;
          if (res[li] == 1 && wbuf[li] != 1) { zidx = li; break; }
          if (res[ri] == 1 && wbuf[ri] != 1) { zidx = ri; break; }
        }
        if (zidx >= 0) res[zidx] = 0;
        res[j] = 1;
      }
    }
    __syncthreads();

    const int L = L_sh;
    for (int t = tid; t < TT; t += 512)
      out2[(size_t)b * TT + t] = (t >= 1 && t < L - 1) ? (float)res[t] : 0.f;
    __syncthreads();   // drain before next rep resets L_sh
  }
}

extern "C" void kernel_launch(void* const* d_in, const int* in_sizes, int n_in,
                              void* d_out, int out_size, void* d_ws, size_t ws_size,
                              hipStream_t stream) {
  const float* feat        = (const float*)d_in[0];
  const int*   word_bd     = (const int*)d_in[1];
  const float* non_padding = (const float*)d_in[2];
  const float* W           = (const float*)d_in[3];
  const float* bias        = (const float*)d_in[4];

  float* out  = (float*)d_out;
  float* out0 = out;
  float* out1 = out + (size_t)NB * TT;
  float* out2 = out + (size_t)NB * TT + (size_t)NB * TT * (CC - 1);

  unsigned short* Wb = (unsigned short*)d_ws;   // 112*256 bf16 = 57344 B

  hipLaunchKernelGGL(wconv_kernel, dim3(112), dim3(256), 0, stream, W, Wb);
  // gemm at 2x grid (idempotent double write) -> exact dur + counters in top-5
  hipLaunchKernelGGL(gemm_mfma, dim3(2 * NGRID), dim3(512), 0, stream,
                     feat, W, bias, Wb, out0, out1);
  // phase with REPS=4 internal repetition -> exact dur/4 + counters in top-5
  hipLaunchKernelGGL(phase_kernel, dim3(NB), dim3(512), 0, stream,
                     out0, word_bd, non_padding, out2);
}

// Round 14
// 81.842 us; speedup vs baseline: 2.2338x; 2.2338x over previous
//
#include <hip/hip_runtime.h>

#define NB 16
#define TT 6000
#define HH 256
#define CC 105
#define MIN_GAP_ 19
#define REF_GAP_ 9

using short8  = __attribute__((ext_vector_type(8))) short;
using short4v = __attribute__((ext_vector_type(4))) short;
using f32x4   = __attribute__((ext_vector_type(4))) float;

static __device__ __forceinline__ short f2bf(float x) {
  unsigned u = __builtin_bit_cast(unsigned, x);
  unsigned r = (u + 0x7FFFu + ((u >> 16) & 1u)) >> 16;   // RNE
  return (short)r;
}

// ---- one-time W (channels 1..104) f32 -> bf16, zero-padded to 112 rows ----
__global__ __launch_bounds__(256) void wconv_kernel(
    const float* __restrict__ W, unsigned short* __restrict__ Wb) {
  const int idx = blockIdx.x * 256 + threadIdx.x;   // 0..28671 (112*256)
  const int c = idx >> 8, k = idx & 255;
  const float v = (c < CC - 1) ? W[(size_t)(c + 1) * HH + k] : 0.f;
  Wb[idx] = (unsigned short)f2bf(v);
}

// ---- GEMM: R8 config (best), 1x grid. B in LDS (56KB swizzled, 2 blk/CU),
// ---- A per-lane global with 16-deep MLP (launch_bounds(512,4)).
#define NGRID 750

__global__ __launch_bounds__(512, 4) void gemm_mfma(
    const float* __restrict__ feat, const float* __restrict__ W,
    const float* __restrict__ bias, const unsigned short* __restrict__ Wb,
    float* __restrict__ out0, float* __restrict__ out1) {
  __shared__ __align__(16) unsigned short bS[112 * 256];   // 56 KB, swizzled
  const int tid  = threadIdx.x;
  const int wv   = tid >> 6;
  const int lane = tid & 63;
  const int rl   = lane & 15;
  const int kg   = lane >> 4;
  const int row  = blockIdx.x * 128 + wv * 16 + rl;
  const float* frow = feat + (size_t)row * HH;

  short8 breg[7];
#pragma unroll
  for (int i = 0; i < 7; i++)
    breg[i] = *reinterpret_cast<const short8*>(Wb + (((size_t)(i * 512 + tid)) << 3));

  float4 areg[16];
#pragma unroll
  for (int ks = 0; ks < 8; ks++) {
    const int kk = ks * 32 + kg * 8;
    areg[2 * ks]     = *reinterpret_cast<const float4*>(frow + kk);
    areg[2 * ks + 1] = *reinterpret_cast<const float4*>(frow + kk + 4);
  }

#pragma unroll
  for (int i = 0; i < 7; i++) {
    const int byte = (i * 512 + tid) << 4;
    const int brow = byte >> 9;
    const int boff = byte & 511;
    *reinterpret_cast<short8*>(
        (char*)bS + (brow << 9) + (boff ^ ((brow & 7) << 4))) = breg[i];
  }
  __syncthreads();

  const int xr = (rl & 7) << 4;
  f32x4 acc[7];
#pragma unroll
  for (int n = 0; n < 7; n++) acc[n] = (f32x4){0.f, 0.f, 0.f, 0.f};
  float c0 = 0.f;

#pragma unroll
  for (int ks = 0; ks < 8; ks++) {
    const int kk = ks * 32 + kg * 8;
    const float4 a0 = areg[2 * ks];
    const float4 a1 = areg[2 * ks + 1];
    const float4 w0a = *reinterpret_cast<const float4*>(W + kk);
    const float4 w0b = *reinterpret_cast<const float4*>(W + kk + 4);
    c0 = fmaf(a0.x, w0a.x, c0); c0 = fmaf(a0.y, w0a.y, c0);
    c0 = fmaf(a0.z, w0a.z, c0); c0 = fmaf(a0.w, w0a.w, c0);
    c0 = fmaf(a1.x, w0b.x, c0); c0 = fmaf(a1.y, w0b.y, c0);
    c0 = fmaf(a1.z, w0b.z, c0); c0 = fmaf(a1.w, w0b.w, c0);

    short8 av;
    av[0] = f2bf(a0.x); av[1] = f2bf(a0.y); av[2] = f2bf(a0.z); av[3] = f2bf(a0.w);
    av[4] = f2bf(a1.x); av[5] = f2bf(a1.y); av[6] = f2bf(a1.z); av[7] = f2bf(a1.w);

    const int boff = (ks * 64 + kg * 16) ^ xr;
    const char* bbase = (const char*)bS + boff;
    short8 bv[7];
#pragma unroll
    for (int n = 0; n < 7; n++)
      bv[n] = *reinterpret_cast<const short8*>(bbase + ((n * 16 + rl) << 9));
#pragma unroll
    for (int n = 0; n < 7; n++)
      acc[n] = __builtin_amdgcn_mfma_f32_16x16x32_bf16(av, bv[n], acc[n], 0, 0, 0);
  }

  c0 += __shfl_xor(c0, 16);
  c0 += __shfl_xor(c0, 32);
  if (kg == 0) out0[row] = fminf(fmaxf(c0 + bias[0], -16.f), 16.f);

  const int rbase = blockIdx.x * 128 + wv * 16 + kg * 4;
#pragma unroll
  for (int n = 0; n < 7; n++) {
    const int c = n * 16 + rl;
    if (c < CC - 1) {
      const float bb = bias[c + 1];
#pragma unroll
      for (int r = 0; r < 4; r++)
        out1[(size_t)(rbase + r) * (CC - 1) + c] = acc[n][r] + bb;
    }
  }
}

// ---- phase v2: 1024 threads; spec/replay are wave-cooperative via shfl
// ---- (register broadcasts replace dependent-LDS inner loops).
#define NW 192
#define NW_LAST 187
#define CHUNK 32
#define NCLS 19
#define MAXRUNS 3072
#define MAXCH 96

__global__ __launch_bounds__(1024) void phase_kernel(
    const float* __restrict__ bd_logits,
    const int* __restrict__ word_bd,
    const float* __restrict__ non_padding,
    float* __restrict__ out2) {
  __shared__ __align__(16) float lbuf[TT];
  __shared__ unsigned char wbuf[TT];
  __shared__ int res[TT];
  __shared__ unsigned bdbits[NW];
  __shared__ int runIdx[MAXRUNS];
  __shared__ int outLast[MAXCH][NCLS + 1];
  __shared__ int chP0[MAXCH];
  __shared__ int inL[MAXCH + 1];
  __shared__ int wsum[16];
  __shared__ int wbase[16];
  __shared__ int L_sh, nruns_sh;

  const int b = blockIdx.x;
  const int tid = threadIdx.x;
  const int lane = tid & 63;
  const int wv = tid >> 6;          // wave 0..15
  if (tid == 0) L_sh = 0;
  __syncthreads();

  // ---- load + bd bitmask via ballot ----
  int cnt_np = 0;
#pragma unroll
  for (int k = 0; k < 6; k++) {
    const int j = k * 1024 + tid;
    bool pred = false;
    if (j < TT) {
      const float l = bd_logits[(size_t)b * TT + j];
      lbuf[j] = l;
      pred = l > 0.f;
      wbuf[j] = (unsigned char)word_bd[(size_t)b * TT + j];
      res[j] = 0;
      cnt_np += (non_padding[(size_t)b * TT + j] != 0.f) ? 1 : 0;
    }
    const unsigned long long m = __ballot(pred);
    if (lane == 0) {
      const int w0 = (k * 1024 + (tid & ~63)) >> 5;
      bdbits[w0]     = (unsigned)m;
      bdbits[w0 + 1] = (unsigned)(m >> 32);
    }
  }
#pragma unroll
  for (int off = 32; off; off >>= 1) cnt_np += __shfl_xor(cnt_np, off);
  if (lane == 0) atomicAdd(&L_sh, cnt_np);
  __syncthreads();

  // ---- run-end detection per 32-bit word ----
  int cnt = 0;
  unsigned ends = 0;
  if (tid < NW) {
    const unsigned cur = bdbits[tid];
    const unsigned pb = tid ? (bdbits[tid - 1] >> 31) : 0u;
    ends = ((cur << 1) | pb) & ~cur;
    if (tid == NW_LAST) ends &= 0xFFFFu;
    cnt = __popc(ends);
  }
  int v = cnt;
#pragma unroll
  for (int off = 1; off < 64; off <<= 1) {
    const int t = __shfl_up(v, off);
    if (lane >= off) v += t;
  }
  if (lane == 63) wsum[wv] = v;
  __syncthreads();
  if (tid == 0) {
    int s = 0;
#pragma unroll
    for (int w = 0; w < 16; w++) { wbase[w] = s; s += wsum[w]; }
    nruns_sh = s;
  }
  __syncthreads();
  int slot = wbase[wv] + v - cnt;

  // ---- emit per-run argmax (forward, strict > = first-max) ----
  if (ends) {
    unsigned m = ends;
    while (m) {
      const int bit = __builtin_ctz(m);
      m &= m - 1;
      const int e = tid * 32 + bit;
      const int eb = e - 1;
      int w = eb >> 5;
      const int bb = eb & 31;
      const unsigned z = bdbits[w] << (31 - bb);
      const unsigned nz = ~z;
      int run = nz ? __builtin_clz(nz) : 32;
      if (run == bb + 1) {
        while (w > 0) {
          w--;
          const unsigned nx = ~bdbits[w];
          const int t2 = nx ? __builtin_clz(nx) : 32;
          run += t2;
          if (t2 < 32) break;
        }
      }
      const int s = e - run;
      float mv = lbuf[s];
      int mi = s;
      for (int i = s + 1; i < e; i++) {
        const float val = lbuf[i];
        if (val > mv) { mv = val; mi = i; }
      }
      runIdx[slot++] = mi;
    }
  }
  __syncthreads();

  // ---- spec sims, wave-cooperative: lane l holds runIdx[s+l]; 19 class
  // ---- lanes simulate via shfl broadcasts (no LDS in inner loop) ----
  const int n = nruns_sh;
  const int nch = (n + CHUNK - 1) / CHUNK;
  for (int ch = wv; ch < nch; ch += 16) {
    const int s = ch * CHUNK;
    const int e = (s + CHUNK < n) ? s + CHUNK : n;
    const int m = e - s;
    const int myrun = (lane < m) ? runIdx[s + lane] : 0;
    const int p0 = __shfl(myrun, 0);
    if (lane == 0) chP0[ch] = p0;
    int last = (lane < 18) ? (p0 - 18 + lane) : -1;
    for (int i = 0; i < m; i++) {
      int bd = __shfl(myrun, i);
      if (last > 0 && bd - last < MIN_GAP_) {
        const int sum = bd + last;
        const int h = sum >> 1;
        bd = (sum & 1) ? (h + (h & 1)) : h;   // round half to even
      }
      last = bd;
    }
    if (lane < NCLS) outLast[ch][lane] = last;
  }
  __syncthreads();

  // ---- stitch: serial over chunks, O(1) per chunk via shfl-select ----
  if (wv == 0) {
    int q = -1;
    int row = (lane < NCLS && nch > 0) ? outLast[0][lane] : -1;
    for (int ch = 0; ch < nch; ch++) {
      const int rown = (lane < NCLS && ch + 1 < nch) ? outLast[ch + 1][lane] : -1;
      const int p0 = chP0[ch];
      const int cls = (q > 0 && p0 - q < MIN_GAP_) ? (q - (p0 - 18)) : (NCLS - 1);
      if (lane == 0) inL[ch] = q;
      q = __shfl(row, cls);
      row = rown;
    }
    if (lane == 0) inL[nch] = q;
  }
  __syncthreads();

  // ---- replay, wave-cooperative: all lanes compute the chain from shfl'd
  // ---- values; lane i performs step i's res writes (order preserved) ----
  for (int ch = wv; ch < nch; ch += 16) {
    const int s = ch * CHUNK;
    const int e = (s + CHUNK < n) ? s + CHUNK : n;
    const int m = e - s;
    const int myrun = (lane < m) ? runIdx[s + lane] : 0;
    const int qin = inL[ch];
    const int qout = inL[ch + 1];
    if (lane == 0 && qin >= 0 && qin != qout) res[qin] = 1;
    int last = qin;
    for (int i = 0; i < m; i++) {
      int bd = __shfl(myrun, i);
      const bool mg = (last > 0 && bd - last < MIN_GAP_);
      if (mg) {
        const int sum = bd + last;
        const int h = sum >> 1;
        bd = (sum & 1) ? (h + (h & 1)) : h;
        if (lane == i && last != qout) res[last] = 0;
      }
      if (lane == i && bd != qout) res[bd] = 1;
      last = bd;
    }
  }
  if (tid == 0 && n > 0) res[inL[nch]] = 1;
  __syncthreads();

  // ---- phase 2: parallel over word boundaries (>=25 apart, +-9 windows) ----
  for (int j = tid; j < TT; j += 1024) {
    if (wbuf[j] != 1) continue;
    const int lo = (j - REF_GAP_ < 0) ? 0 : j - REF_GAP_;
    const int hi = (j + REF_GAP_ - 1 > TT - 1) ? TT - 1 : j + REF_GAP_ - 1;
    int seg = 0;
    for (int w = lo; w <= hi; w++) seg += res[w];
    if (seg == 0) {
      res[j] = 1;
    } else if (seg == 1) {
      if (res[j] != 1) {
        for (int w = lo; w <= hi; w++) res[w] = (int)wbuf[w];
      }
    } else {
      int zidx = -1;
      for (int k = 1; k <= REF_GAP_; k++) {
        const int li = (j - k < 0) ? 0 : j - k;
        const int ri = (j + k > TT - 1) ? TT - 1 : j + k;
        if (res[li] == 1 && wbuf[li] != 1) { zidx = li; break; }
        if (res[ri] == 1 && wbuf[ri] != 1) { zidx = ri; break; }
      }
      if (zidx >= 0) res[zidx] = 0;
      res[j] = 1;
    }
  }
  __syncthreads();

  const int L = L_sh;
  for (int t = tid; t < TT; t += 1024)
    out2[(size_t)b * TT + t] = (t >= 1 && t < L - 1) ? (float)res[t] : 0.f;
}

extern "C" void kernel_launch(void* const* d_in, const int* in_sizes, int n_in,
                              void* d_out, int out_size, void* d_ws, size_t ws_size,
                              hipStream_t stream) {
  const float* feat        = (const float*)d_in[0];
  const int*   word_bd     = (const int*)d_in[1];
  const float* non_padding = (const float*)d_in[2];
  const float* W           = (const float*)d_in[3];
  const float* bias        = (const float*)d_in[4];

  float* out  = (float*)d_out;
  float* out0 = out;
  float* out1 = out + (size_t)NB * TT;
  float* out2 = out + (size_t)NB * TT + (size_t)NB * TT * (CC - 1);

  unsigned short* Wb = (unsigned short*)d_ws;   // 112*256 bf16 = 57344 B

  hipLaunchKernelGGL(wconv_kernel, dim3(112), dim3(256), 0, stream, W, Wb);
  hipLaunchKernelGGL(gemm_mfma, dim3(NGRID), dim3(512), 0, stream,
                     feat, W, bias, Wb, out0, out1);
  hipLaunchKernelGGL(phase_kernel, dim3(NB), dim3(1024), 0, stream,
                     out0, word_bd, non_padding, out2);
}

// Round 15
// 65.940 us; speedup vs baseline: 2.7725x; 1.2412x over previous
//
#include <hip/hip_runtime.h>

#define NB 16
#define TT 6000
#define HH 256
#define CC 105
#define MIN_GAP_ 19
#define REF_GAP_ 9

using short8  = __attribute__((ext_vector_type(8))) short;
using short4v = __attribute__((ext_vector_type(4))) short;
using f32x4   = __attribute__((ext_vector_type(4))) float;

static __device__ __forceinline__ short f2bf(float x) {
  unsigned u = __builtin_bit_cast(unsigned, x);
  unsigned r = (u + 0x7FFFu + ((u >> 16) & 1u)) >> 16;   // RNE
  return (short)r;
}

// ---- GEMM (R8 config, wconv fused): B converted f32->bf16 inline during
// ---- LDS staging (56KB swizzled, 2 blocks/CU); A per-lane global with
// ---- 16-deep MLP (launch_bounds(512,4) -> VGPR cap 128). BM=128, grid 750.
#define NGRID 750

__global__ __launch_bounds__(512, 4) void gemm_mfma(
    const float* __restrict__ feat, const float* __restrict__ W,
    const float* __restrict__ bias,
    float* __restrict__ out0, float* __restrict__ out1) {
  __shared__ __align__(16) unsigned short bS[112 * 256];   // 56 KB, swizzled
  const int tid  = threadIdx.x;
  const int wv   = tid >> 6;        // wave 0..7
  const int lane = tid & 63;
  const int rl   = lane & 15;
  const int kg   = lane >> 4;
  const int row  = blockIdx.x * 128 + wv * 16 + rl;
  const float* frow = feat + (size_t)row * HH;

  // ---- issue ALL 16 A loads first (256B/lane in flight) ----
  float4 areg[16];
#pragma unroll
  for (int ks = 0; ks < 8; ks++) {
    const int kk = ks * 32 + kg * 8;
    areg[2 * ks]     = *reinterpret_cast<const float4*>(frow + kk);
    areg[2 * ks + 1] = *reinterpret_cast<const float4*>(frow + kk + 4);
  }

  // ---- stage B: W rows 1..104 (f32, L2-resident) -> bf16 -> swizzled LDS.
  // chunk c16 = one 16B bf16 chunk; rows 104..111 zeroed (pad).
#pragma unroll
  for (int i = 0; i < 7; i++) {
    const int c16 = i * 512 + tid;          // 0..3583; valid < 3328
    const int brow = c16 >> 5;
    const int boff = (c16 & 31) << 4;
    char* dst = (char*)bS + (brow << 9) + (boff ^ ((brow & 7) << 4));
    if (c16 < 3328) {
      const float* src = W + ((size_t)(brow + 1) << 8) + ((c16 & 31) << 3);
      const float4 f0 = *reinterpret_cast<const float4*>(src);
      const float4 f1 = *reinterpret_cast<const float4*>(src + 4);
      short8 bv;
      bv[0] = f2bf(f0.x); bv[1] = f2bf(f0.y); bv[2] = f2bf(f0.z); bv[3] = f2bf(f0.w);
      bv[4] = f2bf(f1.x); bv[5] = f2bf(f1.y); bv[6] = f2bf(f1.z); bv[7] = f2bf(f1.w);
      *reinterpret_cast<short8*>(dst) = bv;
    } else {
      *reinterpret_cast<short8*>(dst) = (short8){0, 0, 0, 0, 0, 0, 0, 0};
    }
  }
  __syncthreads();

  // ---- main loop: c0 f32 dot (bit-identical order) + bf16 MFMA sweep ----
  const int xr = (rl & 7) << 4;
  f32x4 acc[7];
#pragma unroll
  for (int n = 0; n < 7; n++) acc[n] = (f32x4){0.f, 0.f, 0.f, 0.f};
  float c0 = 0.f;

#pragma unroll
  for (int ks = 0; ks < 8; ks++) {
    const int kk = ks * 32 + kg * 8;
    const float4 a0 = areg[2 * ks];
    const float4 a1 = areg[2 * ks + 1];
    const float4 w0a = *reinterpret_cast<const float4*>(W + kk);
    const float4 w0b = *reinterpret_cast<const float4*>(W + kk + 4);
    c0 = fmaf(a0.x, w0a.x, c0); c0 = fmaf(a0.y, w0a.y, c0);
    c0 = fmaf(a0.z, w0a.z, c0); c0 = fmaf(a0.w, w0a.w, c0);
    c0 = fmaf(a1.x, w0b.x, c0); c0 = fmaf(a1.y, w0b.y, c0);
    c0 = fmaf(a1.z, w0b.z, c0); c0 = fmaf(a1.w, w0b.w, c0);

    short8 av;
    av[0] = f2bf(a0.x); av[1] = f2bf(a0.y); av[2] = f2bf(a0.z); av[3] = f2bf(a0.w);
    av[4] = f2bf(a1.x); av[5] = f2bf(a1.y); av[6] = f2bf(a1.z); av[7] = f2bf(a1.w);

    const int boff = (ks * 64 + kg * 16) ^ xr;
    const char* bbase = (const char*)bS + boff;
    short8 bv[7];
#pragma unroll
    for (int n = 0; n < 7; n++)
      bv[n] = *reinterpret_cast<const short8*>(bbase + ((n * 16 + rl) << 9));
#pragma unroll
    for (int n = 0; n < 7; n++)
      acc[n] = __builtin_amdgcn_mfma_f32_16x16x32_bf16(av, bv[n], acc[n], 0, 0, 0);
  }

  c0 += __shfl_xor(c0, 16);
  c0 += __shfl_xor(c0, 32);
  if (kg == 0) out0[row] = fminf(fmaxf(c0 + bias[0], -16.f), 16.f);

  // D layout: col = lane&15, row = (lane>>4)*4 + reg  [m89]
  const int rbase = blockIdx.x * 128 + wv * 16 + kg * 4;
#pragma unroll
  for (int n = 0; n < 7; n++) {
    const int c = n * 16 + rl;
    if (c < CC - 1) {
      const float bb = bias[c + 1];
#pragma unroll
      for (int r = 0; r < 4; r++)
        out1[(size_t)(rbase + r) * (CC - 1) + c] = acc[n][r] + bb;
    }
  }
}

// ---- phase (proven R8/R12 version): bitwise run detect + chunk-speculative
// ---- merge + parallel phase 2. 512 threads, one block per batch.
#define NW 192
#define NW_LAST 187
#define CHUNK 32
#define NCLS 19
#define MAXRUNS 3072
#define MAXCH 96

__global__ __launch_bounds__(512) void phase_kernel(
    const float* __restrict__ bd_logits,
    const int* __restrict__ word_bd,
    const float* __restrict__ non_padding,
    float* __restrict__ out2) {
  __shared__ __align__(16) float lbuf[TT];
  __shared__ unsigned char wbuf[TT];
  __shared__ int res[TT];
  __shared__ unsigned bdbits[NW];
  __shared__ int runIdx[MAXRUNS];
  __shared__ int outLast[MAXCH][NCLS + 1];
  __shared__ int chP0[MAXCH];
  __shared__ int inL[MAXCH + 1];
  __shared__ int wsum[8];
  __shared__ int wbase[8];
  __shared__ int L_sh, nruns_sh;

  const int b = blockIdx.x;
  const int tid = threadIdx.x;
  const int lane = tid & 63;
  const int wid = tid >> 6;
  if (tid == 0) L_sh = 0;
  __syncthreads();

  int cnt_np = 0;
#pragma unroll
  for (int k = 0; k < 12; k++) {
    const int j = k * 512 + tid;
    bool pred = false;
    if (j < TT) {
      const float l = bd_logits[(size_t)b * TT + j];
      lbuf[j] = l;
      pred = l > 0.f;
      wbuf[j] = (unsigned char)word_bd[(size_t)b * TT + j];
      res[j] = 0;
      cnt_np += (non_padding[(size_t)b * TT + j] != 0.f) ? 1 : 0;
    }
    const unsigned long long m = __ballot(pred);
    if (lane == 0) {
      const int w0 = (k * 512 + (tid & ~63)) >> 5;
      bdbits[w0]     = (unsigned)m;
      bdbits[w0 + 1] = (unsigned)(m >> 32);
    }
  }
#pragma unroll
  for (int off = 32; off; off >>= 1) cnt_np += __shfl_xor(cnt_np, off);
  if (lane == 0) atomicAdd(&L_sh, cnt_np);
  __syncthreads();

  int cnt = 0;
  unsigned ends = 0;
  if (tid < NW) {
    const unsigned cur = bdbits[tid];
    const unsigned pb = tid ? (bdbits[tid - 1] >> 31) : 0u;
    ends = ((cur << 1) | pb) & ~cur;
    if (tid == NW_LAST) ends &= 0xFFFFu;
    cnt = __popc(ends);
  }
  int v = cnt;
#pragma unroll
  for (int off = 1; off < 64; off <<= 1) {
    const int t = __shfl_up(v, off);
    if (lane >= off) v += t;
  }
  if (lane == 63) wsum[wid] = v;
  __syncthreads();
  if (tid == 0) {
    int s = 0;
#pragma unroll
    for (int w = 0; w < 8; w++) { wbase[w] = s; s += wsum[w]; }
    nruns_sh = s;
  }
  __syncthreads();
  int slot = wbase[wid] + v - cnt;

  if (ends) {
    unsigned m = ends;
    while (m) {
      const int bit = __builtin_ctz(m);
      m &= m - 1;
      const int e = tid * 32 + bit;
      const int eb = e - 1;
      int w = eb >> 5;
      const int bb = eb & 31;
      const unsigned z = bdbits[w] << (31 - bb);
      const unsigned nz = ~z;
      int run = nz ? __builtin_clz(nz) : 32;
      if (run == bb + 1) {
        while (w > 0) {
          w--;
          const unsigned nx = ~bdbits[w];
          const int t2 = nx ? __builtin_clz(nx) : 32;
          run += t2;
          if (t2 < 32) break;
        }
      }
      const int s = e - run;
      float mv = lbuf[s];
      int mi = s;
      for (int i = s + 1; i < e; i++) {
        const float val = lbuf[i];
        if (val > mv) { mv = val; mi = i; }
      }
      runIdx[slot++] = mi;
    }
  }
  __syncthreads();

  const int n = nruns_sh;
  const int nch = (n + CHUNK - 1) / CHUNK;
  for (int f = tid; f < nch * NCLS; f += 512) {
    const int ch = f / NCLS;
    const int cls = f - ch * NCLS;
    const int s = ch * CHUNK;
    const int e = (s + CHUNK < n) ? s + CHUNK : n;
    const int p0 = runIdx[s];
    if (cls == NCLS - 1) chP0[ch] = p0;
    int last = (cls < 18) ? (p0 - 18 + cls) : -1;
    for (int i = s; i < e; i++) {
      int bd = runIdx[i];
      if (last > 0 && bd - last < MIN_GAP_) {
        const int sum = bd + last;
        const int h = sum >> 1;
        bd = (sum & 1) ? (h + (h & 1)) : h;
      }
      last = bd;
    }
    outLast[ch][cls] = last;
  }
  __syncthreads();

  if (wid == 0) {
    int q = -1;
    int row = (lane < NCLS && nch > 0) ? outLast[0][lane] : -1;
    for (int ch = 0; ch < nch; ch++) {
      const int rown = (lane < NCLS && ch + 1 < nch) ? outLast[ch + 1][lane] : -1;
      const int p0 = chP0[ch];
      const int cls = (q > 0 && p0 - q < MIN_GAP_) ? (q - (p0 - 18)) : (NCLS - 1);
      if (lane == 0) inL[ch] = q;
      q = __shfl(row, cls);
      row = rown;
    }
    if (lane == 0) inL[nch] = q;
  }
  __syncthreads();

  for (int ch = tid; ch < nch; ch += 512) {
    const int s = ch * CHUNK;
    const int e = (s + CHUNK < n) ? s + CHUNK : n;
    const int qin = inL[ch];
    const int qout = inL[ch + 1];
    if (qin >= 0 && qin != qout) res[qin] = 1;
    int last = qin;
    for (int i = s; i < e; i++) {
      int bd = runIdx[i];
      if (last > 0 && bd - last < MIN_GAP_) {
        const int sum = bd + last;
        const int h = sum >> 1;
        bd = (sum & 1) ? (h + (h & 1)) : h;
        if (last != qout) res[last] = 0;
      }
      if (bd != qout) res[bd] = 1;
      last = bd;
    }
  }
  if (tid == 0 && n > 0) res[inL[nch]] = 1;
  __syncthreads();

  for (int j = tid; j < TT; j += 512) {
    if (wbuf[j] != 1) continue;
    const int lo = (j - REF_GAP_ < 0) ? 0 : j - REF_GAP_;
    const int hi = (j + REF_GAP_ - 1 > TT - 1) ? TT - 1 : j + REF_GAP_ - 1;
    int seg = 0;
    for (int w = lo; w <= hi; w++) seg += res[w];
    if (seg == 0) {
      res[j] = 1;
    } else if (seg == 1) {
      if (res[j] != 1) {
        for (int w = lo; w <= hi; w++) res[w] = (int)wbuf[w];
      }
    } else {
      int zidx = -1;
      for (int k = 1; k <= REF_GAP_; k++) {
        const int li = (j - k < 0) ? 0 : j - k;
        const int ri = (j + k > TT - 1) ? TT - 1 : j + k;
        if (res[li] == 1 && wbuf[li] != 1) { zidx = li; break; }
        if (res[ri] == 1 && wbuf[ri] != 1) { zidx = ri; break; }
      }
      if (zidx >= 0) res[zidx] = 0;
      res[j] = 1;
    }
  }
  __syncthreads();

  const int L = L_sh;
  for (int t = tid; t < TT; t += 512)
    out2[(size_t)b * TT + t] = (t >= 1 && t < L - 1) ? (float)res[t] : 0.f;
}

extern "C" void kernel_launch(void* const* d_in, const int* in_sizes, int n_in,
                              void* d_out, int out_size, void* d_ws, size_t ws_size,
                              hipStream_t stream) {
  const float* feat        = (const float*)d_in[0];
  const int*   word_bd     = (const int*)d_in[1];
  const float* non_padding = (const float*)d_in[2];
  const float* W           = (const float*)d_in[3];
  const float* bias        = (const float*)d_in[4];

  float* out  = (float*)d_out;
  float* out0 = out;
  float* out1 = out + (size_t)NB * TT;
  float* out2 = out + (size_t)NB * TT + (size_t)NB * TT * (CC - 1);

  hipLaunchKernelGGL(gemm_mfma, dim3(NGRID), dim3(512), 0, stream,
                     feat, W, bias, out0, out1);
  hipLaunchKernelGGL(phase_kernel, dim3(NB), dim3(512), 0, stream,
                     out0, word_bd, non_padding, out2);
}